// Round 9
// baseline (310.229 us; speedup 1.0000x reference)
//
#include <hip/hip_runtime.h>
#include <hip/hip_bf16.h>

typedef __attribute__((ext_vector_type(8))) short v8s;   // 8 x bf16 (4 VGPRs)
typedef __attribute__((ext_vector_type(4))) float v4f;   // float4 / MFMA acc

constexpr int H   = 256;  // hidden channels
constexpr int K2  = 512;  // 2H
constexpr int XS  = 72;   // padded LDS stride (fallback kernel)
constexpr int WS  = 72;
constexpr int XS2 = 264;  // 256 + 8 pad (barrier-free GEMM X tile)

__device__ inline unsigned short f2bf(float f) {         // fp32 -> bf16 bits, RNE
    unsigned int u = __builtin_bit_cast(unsigned int, f);
    u += 0x7FFFu + ((u >> 16) & 1u);
    return (unsigned short)(u >> 16);
}
__device__ inline float bf2f(unsigned short s) {
    return __builtin_bit_cast(float, (unsigned int)s << 16);
}

// ---- pre-kernel: W1 fp32 [512][256] (k-major) -> W1T bf16 [256][512] (n-major) ----
__global__ void w1_transpose_kernel(const float* __restrict__ w1,
                                    unsigned short* __restrict__ w1t) {
    __shared__ float tile[32][33];
    const int bk = blockIdx.x;
    const int bn = blockIdx.y;
    const int tx = threadIdx.x & 31;
    const int ty8 = threadIdx.x >> 5;
#pragma unroll
    for (int i = 0; i < 4; ++i) {
        int ty = i * 8 + ty8;
        tile[ty][tx] = w1[(size_t)(bk * 32 + ty) * H + bn * 32 + tx];
    }
    __syncthreads();
#pragma unroll
    for (int i = 0; i < 4; ++i) {
        int ty = i * 8 + ty8;
        w1t[(size_t)(bn * 32 + ty) * K2 + bk * 32 + tx] = f2bf(tile[tx][ty]);
    }
}

// ---- barrier-free GEMM: P = user@W1[:256]+b1 ; Q = movie@W1[256:] (bf16 out) ----
// 256 thr = 4 waves; block tile 64x256; wave tile 64x64; K=256 staged ONCE in LDS;
// W fragments stream from L2 into registers (no barrier in K-loop -> vmcnt pipelining).
__global__ __launch_bounds__(256, 4) void emb_gemm2_kernel(
    const float* __restrict__ user_emb,
    const float* __restrict__ movie_emb,
    const unsigned short* __restrict__ w1t, // [256][512] bf16
    const float* __restrict__ b1,           // [256]
    unsigned short* __restrict__ P,         // [n_users][256] bf16
    unsigned short* __restrict__ Q,         // [n_movies][256] bf16
    const int n_users, const int n_movies, const int nbu)
{
    __shared__ unsigned short Xs[64 * XS2]; // 33792 B

    const int isMovie = (blockIdx.x >= nbu) ? 1 : 0;
    const float* emb  = isMovie ? movie_emb : user_emb;
    unsigned short* outp = isMovie ? Q : P;
    const int  M    = isMovie ? n_movies : n_users;
    const int  kofs = isMovie ? 256 : 0;
    const long m0   = (long)(blockIdx.x - (isMovie ? nbu : 0)) * 64;

    const int t    = threadIdx.x;
    const int wn   = t >> 6;      // wave id = n-slice 0..3
    const int lane = t & 63;
    const int quad = lane >> 4;
    const int l16  = lane & 15;

    // ---- stage entire X tile: 64 rows x 256 k, fp32 -> bf16 ----
    {
        const int xr = t >> 2;            // 0..63
        const int xc = t & 3;             // quarter of the row
        long mr = m0 + xr; if (mr >= M) mr = M - 1;
        const float* arow = emb + (size_t)mr * H + xc * 64;
        unsigned short* dst = Xs + xr * XS2 + xc * 64;
#pragma unroll
        for (int it = 0; it < 4; ++it) {
            v4f a0 = *(const v4f*)(arow + it * 16);
            v4f a1 = *(const v4f*)(arow + it * 16 + 4);
            v4f a2 = *(const v4f*)(arow + it * 16 + 8);
            v4f a3 = *(const v4f*)(arow + it * 16 + 12);
            v8s x0, x1;
#pragma unroll
            for (int i = 0; i < 4; ++i) { x0[i] = (short)f2bf(a0[i]); x0[4+i] = (short)f2bf(a1[i]); }
#pragma unroll
            for (int i = 0; i < 4; ++i) { x1[i] = (short)f2bf(a2[i]); x1[4+i] = (short)f2bf(a3[i]); }
            *(v8s*)(dst + it * 16)     = x0;
            *(v8s*)(dst + it * 16 + 8) = x1;
        }
    }

    v4f acc[4][4];
#pragma unroll
    for (int mt = 0; mt < 4; ++mt)
#pragma unroll
        for (int nt = 0; nt < 4; ++nt)
            acc[mt][nt] = (v4f){0.f, 0.f, 0.f, 0.f};

    __syncthreads();   // the ONLY barrier: X tile visible, K-loop below is drain-free

    // B fragment source: row (wn*64 + nt*16 + l16) of n-major W1T, k = kofs + k0 + quad*8
    const unsigned short* wbase = w1t + (size_t)(wn * 64 + l16) * K2 + kofs + quad * 8;

#pragma unroll
    for (int kt = 0; kt < 4; ++kt) {
#pragma unroll
        for (int ks = 0; ks < 2; ++ks) {
            const int k0 = kt * 64 + ks * 32;
            v8s af[4], bf[4];
#pragma unroll
            for (int nt = 0; nt < 4; ++nt)            // global (L2) -> regs, pipelined
                bf[nt] = *(const v8s*)(wbase + (size_t)nt * 16 * K2 + k0);
#pragma unroll
            for (int mt = 0; mt < 4; ++mt)            // LDS -> regs
                af[mt] = *(const v8s*)(Xs + (mt * 16 + l16) * XS2 + k0 + quad * 8);
#pragma unroll
            for (int mt = 0; mt < 4; ++mt)
#pragma unroll
                for (int nt = 0; nt < 4; ++nt)
                    acc[mt][nt] = __builtin_amdgcn_mfma_f32_16x16x32_bf16(
                        af[mt], bf[nt], acc[mt][nt], 0, 0, 0);
        }
    }

    // ---- epilogue: (+b1 on user side), bf16 store. D: col=l16, row=quad*4+j ----
    float bv[4];
#pragma unroll
    for (int nt = 0; nt < 4; ++nt)
        bv[nt] = isMovie ? 0.f : b1[wn * 64 + nt * 16 + l16];

#pragma unroll
    for (int mt = 0; mt < 4; ++mt) {
#pragma unroll
        for (int j = 0; j < 4; ++j) {
            long m = m0 + mt * 16 + quad * 4 + j;
            if (m < M) {
#pragma unroll
                for (int nt = 0; nt < 4; ++nt) {
                    int n = wn * 64 + nt * 16 + l16;
                    outp[(size_t)m * H + n] = f2bf(acc[mt][nt][j] + bv[nt]);
                }
            }
        }
    }
}

// ---- edge pass: out[e] = relu(P[u] + Q[m]) . w2 + b2 ----
__global__ __launch_bounds__(256, 8) void edge_score_kernel(
    const unsigned short* __restrict__ P,
    const unsigned short* __restrict__ Q,
    const int* __restrict__ eli,
    const float* __restrict__ w2,
    const float* __restrict__ b2,
    float* __restrict__ out,
    const int E, const int n_users, const int n_movies)
{
    const int t   = threadIdx.x;
    const int hw  = t >> 5;        // 0..7
    const int l32 = t & 31;

    float w2v[8];
    {
        v4f a = *(const v4f*)(w2 + l32 * 8);
        v4f b = *(const v4f*)(w2 + l32 * 8 + 4);
#pragma unroll
        for (int i = 0; i < 4; ++i) { w2v[i] = a[i]; w2v[4 + i] = b[i]; }
    }
    const float b2v = b2[0];
    const long base = (long)blockIdx.x * 64;

    int us[8], ms[8];
#pragma unroll
    for (int i = 0; i < 8; ++i) {
        long e = base + i * 8 + hw;
        long ec = (e < E) ? e : 0;
        int u = eli[ec];
        int m = eli[(long)E + ec];
        us[i] = u < 0 ? 0 : (u >= n_users  ? n_users  - 1 : u);
        ms[i] = m < 0 ? 0 : (m >= n_movies ? n_movies - 1 : m);
    }

    v8s pv = *(const v8s*)(P + (size_t)us[0] * H + l32 * 8);
    v8s qv = *(const v8s*)(Q + (size_t)ms[0] * H + l32 * 8);

#pragma unroll
    for (int i = 0; i < 8; ++i) {
        v8s pn, qn;
        if (i < 7) {
            pn = *(const v8s*)(P + (size_t)us[i + 1] * H + l32 * 8);
            qn = *(const v8s*)(Q + (size_t)ms[i + 1] * H + l32 * 8);
        }
        float s = 0.f;
#pragma unroll
        for (int j = 0; j < 8; ++j) {
            float h = bf2f((unsigned short)pv[j]) + bf2f((unsigned short)qv[j]);
            h = h > 0.f ? h : 0.f;
            s += h * w2v[j];
        }
        s += __shfl_xor(s, 1, 64);
        s += __shfl_xor(s, 2, 64);
        s += __shfl_xor(s, 4, 64);
        s += __shfl_xor(s, 8, 64);
        s += __shfl_xor(s, 16, 64);
        long e = base + i * 8 + hw;
        if (l32 == 0 && e < E) out[e] = s + b2v;
        pv = pn; qv = qn;
    }
}

// ================= round-6 fallback (verified) — used if ws_size too small ==========
constexpr int BMF = 64;
__global__ __launch_bounds__(512, 4) void edge_decoder_kernel(
    const float* __restrict__ user_emb, const float* __restrict__ movie_emb,
    const int* __restrict__ eli, const unsigned short* __restrict__ w1t,
    const float* __restrict__ b1, const float* __restrict__ w2,
    const float* __restrict__ b2, float* __restrict__ out,
    const int E, const int n_users, const int n_movies)
{
    __shared__ unsigned short Xs[BMF * XS];
    __shared__ unsigned short Wts[H * WS];
    __shared__ float red[4][BMF];
    const int t = threadIdx.x, wave = t >> 6, lane = t & 63;
    const int wm = wave >> 2, wn = wave & 3, quad = lane >> 4, l16 = lane & 15;
    const long e0 = (long)blockIdx.x * BMF;
    const int xr = t >> 3, xc = t & 7;
    long eg = e0 + xr; if (eg >= E) eg = 0;
    int iu = eli[eg], im = eli[(long)E + eg];
    iu = iu < 0 ? 0 : (iu >= n_users ? n_users - 1 : iu);
    im = im < 0 ? 0 : (im >= n_movies ? n_movies - 1 : im);
    const float* urow = user_emb + (size_t)iu * H;
    const float* mrow = movie_emb + (size_t)im * H;
    const int wr = t >> 3, wc8 = t & 7;
    const unsigned short* wbase = w1t + (size_t)wr * K2 + wc8 * 8;
    v4f acc[2][4];
#pragma unroll
    for (int mt = 0; mt < 2; ++mt)
#pragma unroll
        for (int nt = 0; nt < 4; ++nt) acc[mt][nt] = (v4f){0.f,0.f,0.f,0.f};
    v4f xq0 = *(const v4f*)(urow + xc * 8);
    v4f xq1 = *(const v4f*)(urow + xc * 8 + 4);
    v8s wq[4];
#pragma unroll
    for (int j = 0; j < 4; ++j) wq[j] = *(const v8s*)(wbase + (size_t)j * 64 * K2);
    for (int kt = 0; kt < 8; ++kt) {
        __syncthreads();
        { v8s xv;
#pragma unroll
          for (int i = 0; i < 4; ++i) xv[i] = (short)f2bf(xq0[i]);
#pragma unroll
          for (int i = 0; i < 4; ++i) xv[4+i] = (short)f2bf(xq1[i]);
          *(v8s*)(Xs + xr * XS + xc * 8) = xv; }
#pragma unroll
        for (int j = 0; j < 4; ++j) *(v8s*)(Wts + (j * 64 + wr) * WS + wc8 * 8) = wq[j];
        if (kt < 7) {
            const int kn = kt + 1, koff = (kn * 64) & 255;
            const float* src = ((kn < 4) ? urow : mrow) + koff + xc * 8;
            xq0 = *(const v4f*)(src); xq1 = *(const v4f*)(src + 4);
#pragma unroll
            for (int j = 0; j < 4; ++j) wq[j] = *(const v8s*)(wbase + (size_t)j * 64 * K2 + kn * 64);
        }
        __syncthreads();
#pragma unroll
        for (int ks = 0; ks < 2; ++ks) {
            v8s af[2], bf[4];
#pragma unroll
            for (int mt = 0; mt < 2; ++mt)
                af[mt] = *(const v8s*)(Xs + (wm * 32 + mt * 16 + l16) * XS + ks * 32 + quad * 8);
#pragma unroll
            for (int nt = 0; nt < 4; ++nt)
                bf[nt] = *(const v8s*)(Wts + (wn * 64 + nt * 16 + l16) * WS + ks * 32 + quad * 8);
#pragma unroll
            for (int mt = 0; mt < 2; ++mt)
#pragma unroll
                for (int nt = 0; nt < 4; ++nt)
                    acc[mt][nt] = __builtin_amdgcn_mfma_f32_16x16x32_bf16(af[mt], bf[nt], acc[mt][nt], 0, 0, 0);
        }
    }
    float b1v[4], w2v[4];
#pragma unroll
    for (int nt = 0; nt < 4; ++nt) {
        int n = wn * 64 + nt * 16 + l16;
        b1v[nt] = b1[n]; w2v[nt] = w2[n];
    }
    const float b2v = b2[0];
#pragma unroll
    for (int mt = 0; mt < 2; ++mt) {
        float s[4] = {0.f,0.f,0.f,0.f};
#pragma unroll
        for (int nt = 0; nt < 4; ++nt)
#pragma unroll
            for (int j = 0; j < 4; ++j) {
                float h = acc[mt][nt][j] + b1v[nt];
                h = h > 0.f ? h : 0.f;
                s[j] += h * w2v[nt];
            }
#pragma unroll
        for (int j = 0; j < 4; ++j) {
            float v = s[j];
            v += __shfl_xor(v, 1, 64); v += __shfl_xor(v, 2, 64);
            v += __shfl_xor(v, 4, 64); v += __shfl_xor(v, 8, 64);
            if (l16 == 0) red[wn][wm * 32 + mt * 16 + quad * 4 + j] = v;
        }
    }
    __syncthreads();
    if (t < BMF) {
        long e = e0 + t;
        if (e < E) out[e] = red[0][t] + red[1][t] + red[2][t] + red[3][t] + b2v;
    }
}

extern "C" void kernel_launch(void* const* d_in, const int* in_sizes, int n_in,
                              void* d_out, int out_size, void* d_ws, size_t ws_size,
                              hipStream_t stream) {
    const float* user_emb  = (const float*)d_in[0];
    const float* movie_emb = (const float*)d_in[1];
    const int*   eli       = (const int*)d_in[2];
    const float* w1        = (const float*)d_in[3];
    const float* b1        = (const float*)d_in[4];
    const float* w2        = (const float*)d_in[5];
    const float* b2        = (const float*)d_in[6];
    float*       out       = (float*)d_out;

    const int E        = out_size;
    const int n_users  = in_sizes[0] / H;
    const int n_movies = in_sizes[1] / H;

    unsigned short* w1t = (unsigned short*)d_ws;                 // 256 KiB
    const size_t w1t_bytes = (size_t)K2 * H * 2;
    const size_t p_bytes   = (size_t)n_users  * H * 2;
    const size_t q_bytes   = (size_t)n_movies * H * 2;

    w1_transpose_kernel<<<dim3(16, 8), 256, 0, stream>>>(w1, w1t);

    if (ws_size >= w1t_bytes + p_bytes + q_bytes) {
        unsigned short* P = (unsigned short*)((char*)d_ws + w1t_bytes);
        unsigned short* Q = (unsigned short*)((char*)d_ws + w1t_bytes + p_bytes);
        const int nbu = (n_users  + 63) / 64;
        const int nbm = (n_movies + 63) / 64;
        emb_gemm2_kernel<<<nbu + nbm, 256, 0, stream>>>(
            user_emb, movie_emb, w1t, b1, P, Q, n_users, n_movies, nbu);
        edge_score_kernel<<<(E + 63) / 64, 256, 0, stream>>>(
            P, Q, eli, w2, b2, out, E, n_users, n_movies);
    } else {
        edge_decoder_kernel<<<(E + BMF - 1) / BMF, 512, 0, stream>>>(
            user_emb, movie_emb, eli, w1t, b1, w2, b2, out, E, n_users, n_movies);
    }
}